// Round 11
// baseline (675.368 us; speedup 1.0000x reference)
//
#include <hip/hip_runtime.h>

// Problem constants
#define NN 50000
#define EE 1600000
#define FF 128
#define HH 64
#define CC 40

// deg hist: 64 edge-chunks x 4 node-slices = 256 blocks
#define NCH 64
#define CHE (EE / NCH)         // 25000
#define NSL 4
#define SLN (NN / NSL)         // 12500

// bucket sort: 250 producers x 250 dst-slices (200 nodes each), capacity 64
#define PA 250
#define EPP (EE / PA)          // 6400
#define SB 250
#define SLNB 200               // NN / SB
#define BCAP 64

// ---------- bf16 helpers (storage-only; math in fp32) ----------
static __device__ __forceinline__ float bf2f(unsigned short u) {
    union { unsigned int i; float f; } c; c.i = ((unsigned int)u) << 16; return c.f;
}
static __device__ __forceinline__ unsigned short f2bf(float x) {  // RNE
    union { float f; unsigned int i; } c; c.f = x;
    unsigned int r = c.i + 0x7FFFu + ((c.i >> 16) & 1u);
    return (unsigned short)(r >> 16);
}

// ---------- deg histogram ----------
__global__ __launch_bounds__(1024) void deg_hist_kernel(
    const int* __restrict__ src, const float* __restrict__ w,
    float* __restrict__ pdeg) {
    __shared__ float ldeg[SLN];
    int s = blockIdx.x % NSL;
    int c = blockIdx.x / NSL;
    int base = s * SLN;
    for (int i = threadIdx.x; i < SLN; i += 1024) ldeg[i] = 0.f;
    __syncthreads();
    int e0 = c * CHE;
    for (int e = e0 + threadIdx.x; e < e0 + CHE; e += 1024) {
        int se = src[e];
        unsigned us = (unsigned)(se - base);
        if (us < SLN) atomicAdd(&ldeg[us], w[e]);
    }
    __syncthreads();
    for (int i = threadIdx.x; i < SLN; i += 1024)
        pdeg[(size_t)c * NN + base + i] = ldeg[i];
}

__global__ void reduce_kernel(const float* __restrict__ pdeg,
                              float* __restrict__ dis, float* __restrict__ diag) {
    int n = blockIdx.x * blockDim.x + threadIdx.x;
    if (n >= NN) return;
    float dsum = 0.f;
    for (int c = 0; c < NCH; ++c) dsum += pdeg[(size_t)c * NN + n];
    dis[n]  = (dsum > 0.f) ? rsqrtf(fmaxf(dsum, 1e-12f)) : 0.f;
    diag[n] = (dsum > 0.f) ? 0.f : -1.f;
}

// ---------- phase A: bin edges by dst-slice ----------
__global__ __launch_bounds__(256) void bucketA_kernel(
    const int* __restrict__ src, const int* __restrict__ dst,
    const float* __restrict__ w, const float* __restrict__ dis,
    uint2* __restrict__ buckets, int* __restrict__ counts) {
    __shared__ int lcnt[SB];
    int p = blockIdx.x;
    for (int i = threadIdx.x; i < SB; i += 256) lcnt[i] = 0;
    __syncthreads();
    int e0 = p * EPP;
    for (int e = e0 + threadIdx.x; e < e0 + EPP; e += 256) {
        int de = dst[e], se = src[e];
        int sl = de / SLNB;
        int dl = de - sl * SLNB;
        float wn = -dis[se] * w[e] * dis[de];
        unsigned lo = (unsigned)se | ((unsigned)f2bf(wn) << 16);
        int idx = atomicAdd(&lcnt[sl], 1);
        buckets[((size_t)p * SB + sl) * BCAP + idx] = make_uint2(lo, (unsigned)dl);
    }
    __syncthreads();
    for (int i = threadIdx.x; i < SB; i += 256) counts[p * SB + i] = lcnt[i];
}

// ---------- exclusive scan of per-slice totals ----------
__global__ void scanS_kernel(const int* __restrict__ counts, int* __restrict__ sbase) {
    __shared__ int sh[256];
    int t = threadIdx.x;
    int total = 0;
    if (t < SB)
        for (int p = 0; p < PA; ++p) total += counts[p * SB + t];
    sh[t] = total;
    __syncthreads();
    for (int off = 1; off < 256; off <<= 1) {
        int x = (t >= off) ? sh[t - off] : 0;
        __syncthreads();
        sh[t] += x;
        __syncthreads();
    }
    if (t < SB) sbase[t] = sh[t] - total;
    if (t == SB - 1) sbase[SB] = sh[t];
}

// ---------- phase B v2: counts in LDS + 16-lane bucket subgroups (16 streams) ----------
__global__ __launch_bounds__(256) void bucketB_kernel(
    const uint2* __restrict__ buckets, const int* __restrict__ counts,
    const int* __restrict__ sbase,
    int* __restrict__ row_start, unsigned int* __restrict__ csr) {
    __shared__ int lcounts[PA];
    __shared__ int lhist[SLNB];
    __shared__ int sh[256];
    int s = blockIdx.x;
    int t = threadIdx.x;
    if (t < PA) lcounts[t] = counts[t * SB + s];
    for (int i = t; i < SLNB; i += 256) lhist[i] = 0;
    __syncthreads();
    int g = t >> 4, l16 = t & 15;   // 16 subgroups x 16 lanes
    // sweep 1: count dstLocal
    for (int p = g; p < PA; p += 16) {
        int c = lcounts[p];
        const uint2* b = buckets + ((size_t)p * SB + s) * BCAP;
        for (int i = l16; i < c; i += 16)
            atomicAdd(&lhist[b[i].y], 1);
    }
    __syncthreads();
    // exclusive scan of lhist over SLNB
    int v = (t < SLNB) ? lhist[t] : 0;
    sh[t] = v;
    __syncthreads();
    for (int off = 1; off < 256; off <<= 1) {
        int x = (t >= off) ? sh[t - off] : 0;
        __syncthreads();
        sh[t] += x;
        __syncthreads();
    }
    int base = sbase[s];
    if (t < SLNB) {
        int excl = sh[t] - v;
        row_start[s * SLNB + t] = base + excl;
        lhist[t] = base + excl;          // absolute cursor
    }
    if (s == SB - 1 && t == 0) row_start[NN] = sbase[SB];
    __syncthreads();
    // sweep 2: place entries
    for (int p = g; p < PA; p += 16) {
        int c = lcounts[p];
        const uint2* b = buckets + ((size_t)p * SB + s) * BCAP;
        for (int i = l16; i < c; i += 16) {
            uint2 en = b[i];
            int pos = atomicAdd(&lhist[en.y], 1);
            csr[pos] = en.x;
        }
    }
}

// ---------- layer-1 propagation: 32-feature half-pass over PACKED [N,32] bf16 ----------
// Gathered array is physically 3.2 MB (64 B rows) -> fits per-XCD 4 MB L2.
// Wave = 2 edges x 32 features (lane = f + 32*es); shfl fold. nt on streams.
template <typename OUT_T>
__global__ __launch_bounds__(256) void prop_half_kernel(
    const unsigned short* __restrict__ a,        // packed [N,32] bf16
    float alphaL,
    const float* __restrict__ p1, float beta1,   // column-base pre-offset, stride 256
    const float* __restrict__ p2, float beta2,
    const float* __restrict__ bias, int doRelu, int outStride,
    const float* __restrict__ diag, const int* __restrict__ rs,
    const unsigned int* __restrict__ csr, OUT_T* __restrict__ out) {
    int lane = threadIdx.x & 63;
    int wave = threadIdx.x >> 6;
    int n = blockIdx.x * 4 + wave;   // NN divisible by 4
    int f = lane & 31;
    int es = lane >> 5;
    float acc = 0.f;
    int j0 = rs[n], j1 = rs[n + 1];
    int j = j0;
    for (; j + 16 <= j1; j += 16) {
        unsigned cw[8];
        #pragma unroll
        for (int u = 0; u < 8; ++u)
            cw[u] = __builtin_nontemporal_load(csr + j + 2 * u + es);
        float v[8];
        #pragma unroll
        for (int u = 0; u < 8; ++u)
            v[u] = bf2f(a[(size_t)(cw[u] & 0xFFFFu) * 32 + f]);
        #pragma unroll
        for (int u = 0; u < 8; ++u)
            acc = fmaf(bf2f((unsigned short)(cw[u] >> 16)), v[u], acc);
    }
    for (; j + 2 <= j1; j += 2) {
        unsigned cw = __builtin_nontemporal_load(csr + j + es);
        acc = fmaf(bf2f((unsigned short)(cw >> 16)),
                   bf2f(a[(size_t)(cw & 0xFFFFu) * 32 + f]), acc);
    }
    if (j < j1 && es == 0) {
        unsigned cw = __builtin_nontemporal_load(csr + j);
        acc = fmaf(bf2f((unsigned short)(cw >> 16)),
                   bf2f(a[(size_t)(cw & 0xFFFFu) * 32 + f]), acc);
    }
    acc += __shfl_down(acc, 32);
    if (es == 0) {
        acc = fmaf(diag[n], bf2f(a[(size_t)n * 32 + f]), acc);
        float r = alphaL * acc
                + beta1 * __builtin_nontemporal_load(p1 + (size_t)n * 256 + f);
        if (beta2 != 0.f)
            r = fmaf(beta2, __builtin_nontemporal_load(p2 + (size_t)n * 256 + f), r);
        if (bias) r += bias[f];
        if (doRelu) r = fmaxf(r, 0.f);
        if constexpr (sizeof(OUT_T) == 2)
            __builtin_nontemporal_store(f2bf(r), out + (size_t)n * outStride + f);
        else
            __builtin_nontemporal_store(r, out + (size_t)n * outStride + f);
    }
}

// ---------- layer-2 propagation (unchanged: stride-64 bf16 gather, 4B CSR) ----------
template <int FACT, typename OUT_T>
__global__ __launch_bounds__(256) void prop2_kernel(
    const unsigned short* __restrict__ a, int aStride, float alphaL,
    const float* __restrict__ p1, float beta1,
    const float* __restrict__ p2, float beta2, int pStride,
    const float* __restrict__ bias, int doRelu, int FOUT, int outStride,
    const float* __restrict__ diag, const int* __restrict__ rs,
    const unsigned int* __restrict__ csr, OUT_T* __restrict__ out) {
    int lane = threadIdx.x & 63;
    int wave = threadIdx.x >> 6;
    int n = blockIdx.x * 4 + wave;
    int f = lane;
    float acc = 0.f;
    if (f < FACT) {
        acc = diag[n] * bf2f(a[(size_t)n * aStride + f]);
        int j0 = rs[n], j1 = rs[n + 1];
        int j = j0;
        for (; j + 8 <= j1; j += 8) {
            unsigned cw[8];
            #pragma unroll
            for (int u = 0; u < 8; ++u) cw[u] = csr[j + u];
            float v[8];
            #pragma unroll
            for (int u = 0; u < 8; ++u)
                v[u] = bf2f(a[(size_t)(cw[u] & 0xFFFFu) * aStride + f]);
            #pragma unroll
            for (int u = 0; u < 8; ++u)
                acc = fmaf(bf2f((unsigned short)(cw[u] >> 16)), v[u], acc);
        }
        for (; j < j1; ++j) {
            unsigned cw = csr[j];
            acc = fmaf(bf2f((unsigned short)(cw >> 16)),
                       bf2f(a[(size_t)(cw & 0xFFFFu) * aStride + f]), acc);
        }
    }
    if (f < FOUT) {
        float r = alphaL * acc + beta1 * p1[(size_t)n * pStride + f];
        if (beta2 != 0.f) r = fmaf(beta2, p2[(size_t)n * pStride + f], r);
        if (bias) r += bias[f];
        if (doRelu) r = fmaxf(r, 0.f);
        OUT_T o;
        if constexpr (sizeof(OUT_T) == 2) o = f2bf(r); else o = r;
        out[(size_t)n * outStride + f] = o;
    }
}

// ---------- GEMM1: Yf fp32 slabs; ct=3 also emits PACKED y3lo/y3hi bf16 [N,32] ----------
__global__ __launch_bounds__(256) void gemm1_kernel(
    const float* __restrict__ x, const float* __restrict__ W,
    float* __restrict__ Yf, unsigned short* __restrict__ y3lo,
    unsigned short* __restrict__ y3hi) {
    __shared__ float As[64][36];
    __shared__ float Bs[32][64];
    int t = threadIdx.x;
    int m0 = blockIdx.x * 64;
    int ct = blockIdx.y;
    int tr = t / 16, tc = t % 16;
    int kq = t % 8,  ms = t / 8;
    int jb = t % 16, fb = t / 16;
    float acc[4][4] = {};
    for (int kb = 0; kb < 4; ++kb) {
        __syncthreads();
        #pragma unroll
        for (int p = 0; p < 2; ++p) {
            int m = ms + 32 * p;
            int row = m0 + m;
            float4 vv = make_float4(0.f, 0.f, 0.f, 0.f);
            if (row < NN) vv = *(const float4*)(x + (size_t)row * FF + kb * 32 + kq * 4);
            *(float4*)&As[m][kq * 4] = vv;
        }
        const float* Wb = W + ((size_t)ct * 128 + kb * 32) * HH;
        #pragma unroll
        for (int p = 0; p < 2; ++p) {
            int fi = fb + 16 * p;
            float4 vv = *(const float4*)(Wb + fi * HH + jb * 4);
            *(float4*)&Bs[fi][jb * 4] = vv;
        }
        __syncthreads();
        #pragma unroll 8
        for (int k = 0; k < 32; ++k) {
            float a0 = As[tr * 4 + 0][k], a1 = As[tr * 4 + 1][k];
            float a2 = As[tr * 4 + 2][k], a3 = As[tr * 4 + 3][k];
            float4 b = *(float4*)&Bs[k][tc * 4];
            acc[0][0] = fmaf(a0, b.x, acc[0][0]); acc[0][1] = fmaf(a0, b.y, acc[0][1]);
            acc[0][2] = fmaf(a0, b.z, acc[0][2]); acc[0][3] = fmaf(a0, b.w, acc[0][3]);
            acc[1][0] = fmaf(a1, b.x, acc[1][0]); acc[1][1] = fmaf(a1, b.y, acc[1][1]);
            acc[1][2] = fmaf(a1, b.z, acc[1][2]); acc[1][3] = fmaf(a1, b.w, acc[1][3]);
            acc[2][0] = fmaf(a2, b.x, acc[2][0]); acc[2][1] = fmaf(a2, b.y, acc[2][1]);
            acc[2][2] = fmaf(a2, b.z, acc[2][2]); acc[2][3] = fmaf(a2, b.w, acc[2][3]);
            acc[3][0] = fmaf(a3, b.x, acc[3][0]); acc[3][1] = fmaf(a3, b.y, acc[3][1]);
            acc[3][2] = fmaf(a3, b.z, acc[3][2]); acc[3][3] = fmaf(a3, b.w, acc[3][3]);
        }
    }
    #pragma unroll
    for (int r = 0; r < 4; ++r) {
        int n = m0 + tr * 4 + r;
        if (n < NN) {
            *(float4*)(Yf + (size_t)n * 256 + ct * 64 + tc * 4) =
                make_float4(acc[r][0], acc[r][1], acc[r][2], acc[r][3]);
            if (ct == 3) {
                ushort4 u4;
                u4.x = f2bf(acc[r][0]); u4.y = f2bf(acc[r][1]);
                u4.z = f2bf(acc[r][2]); u4.w = f2bf(acc[r][3]);
                int j = tc * 4;
                unsigned short* dstp = (j < 32) ? (y3lo + (size_t)n * 32 + j)
                                                : (y3hi + (size_t)n * 32 + (j - 32));
                *(ushort4*)dstp = u4;
            }
        }
    }
}

// ---------- GEMM2: Y2f stride-64 slabs + y3b2 bf16 (unchanged) ----------
__global__ __launch_bounds__(256) void gemm2_kernel(
    const float* __restrict__ h, const float* __restrict__ W,
    float* __restrict__ Y2f, unsigned short* __restrict__ y3b2) {
    __shared__ float As[128][36];
    __shared__ float Bs[32][40];
    int t = threadIdx.x;
    int m0 = blockIdx.x * 128;
    int kt = blockIdx.y;
    int tr = t / 8, tc = t % 8;
    int kq = t % 8, ms = t / 8;
    float acc[4][5] = {};
    for (int kb = 0; kb < 2; ++kb) {
        __syncthreads();
        #pragma unroll
        for (int p = 0; p < 4; ++p) {
            int m = ms + 32 * p;
            int row = m0 + m;
            float4 vv = make_float4(0.f, 0.f, 0.f, 0.f);
            if (row < NN) vv = *(const float4*)(h + (size_t)row * HH + kb * 32 + kq * 4);
            *(float4*)&As[m][kq * 4] = vv;
        }
        const float* Wb = W + ((size_t)kt * 64 + kb * 32) * CC;
        for (int i = t; i < 32 * CC; i += 256) ((float*)Bs)[i] = Wb[i];
        __syncthreads();
        #pragma unroll 4
        for (int k = 0; k < 32; ++k) {
            float a0 = As[tr * 4 + 0][k], a1 = As[tr * 4 + 1][k];
            float a2 = As[tr * 4 + 2][k], a3 = As[tr * 4 + 3][k];
            #pragma unroll
            for (int c = 0; c < 5; ++c) {
                float b = Bs[k][tc * 5 + c];
                acc[0][c] = fmaf(a0, b, acc[0][c]);
                acc[1][c] = fmaf(a1, b, acc[1][c]);
                acc[2][c] = fmaf(a2, b, acc[2][c]);
                acc[3][c] = fmaf(a3, b, acc[3][c]);
            }
        }
    }
    #pragma unroll
    for (int r = 0; r < 4; ++r) {
        int n = m0 + tr * 4 + r;
        if (n < NN) {
            float* orow = Y2f + (size_t)n * 256 + kt * 64;
            #pragma unroll
            for (int c = 0; c < 5; ++c) orow[tc * 5 + c] = acc[r][c];
            if (tc < 6) {
                #pragma unroll
                for (int c = 0; c < 4; ++c) orow[40 + tc * 4 + c] = 0.f;
            }
            if (kt == 3) {
                unsigned short* brow = y3b2 + (size_t)n * 64;
                #pragma unroll
                for (int c = 0; c < 5; ++c) brow[tc * 5 + c] = f2bf(acc[r][c]);
                if (tc < 6) {
                    #pragma unroll
                    for (int c = 0; c < 4; ++c) brow[40 + tc * 4 + c] = 0;
                }
            }
        }
    }
}

// ---------- launcher ----------
extern "C" void kernel_launch(void* const* d_in, const int* in_sizes, int n_in,
                              void* d_out, int out_size, void* d_ws, size_t ws_size,
                              hipStream_t stream) {
    const float* x    = (const float*)d_in[0];
    const int*   eidx = (const int*)d_in[1];
    const float* ew   = (const float*)d_in[2];
    const float* W1   = (const float*)d_in[3];
    const float* b1   = (const float*)d_in[4];
    const float* W2   = (const float*)d_in[5];
    const float* b2   = (const float*)d_in[6];
    float* out = (float*)d_out;

    const int* src = eidx;
    const int* dst = eidx + EE;

    // workspace carve-up
    float* p = (float*)d_ws;
    unsigned int* csr = (unsigned int*)p;  p += (size_t)EE;       // 6.4 MB
    float* dis  = p;                  p += ((NN + 63) / 64) * 64;
    float* diag = p;                  p += ((NN + 63) / 64) * 64;
    float* Yf   = p;                  p += (size_t)NN * 256;      // 51.2 MB
    unsigned short* hv1 = (unsigned short*)p;  p += (size_t)NN * 32;  // 6.4 MB: y3lo|y3hi
    unsigned short* hv2 = (unsigned short*)p;  p += (size_t)NN * 32;  // ulo|uhi
    unsigned short* hv3 = (unsigned short*)p;  p += (size_t)NN * 32;  // vlo|vhi
    float* h    = p;                  p += (size_t)NN * 64;       // fp32 [N,64]
    int* row_start = (int*)p;             // NN+1
    int* counts    = row_start + NN + 1;  // PA*SB
    int* sbase     = counts + PA * SB;    // SB+1

    // packed half-array views (each [N,32] bf16 = 3.2 MB)
    unsigned short* y3lo = hv1;
    unsigned short* y3hi = hv1 + (size_t)NN * 32;
    unsigned short* ulo  = hv2;
    unsigned short* uhi  = hv2 + (size_t)NN * 32;
    unsigned short* vlo  = hv3;
    unsigned short* vhi  = hv3 + (size_t)NN * 32;

    // setup scratch aliases Yf (dead before gemm1 writes Yf)
    float* pdeg    = Yf;
    uint2* buckets = (uint2*)(Yf + (size_t)64 * NN);   // 32 MB
    // layer-2 aliases (layer-1 halves dead after h)
    float* Y2f = Yf;
    unsigned short* y3b2 = hv1;   // [N,64] bf16
    unsigned short* u2 = hv2;
    unsigned short* v2 = hv3;

    const int B = 256;
    deg_hist_kernel<<<NCH * NSL, 1024, 0, stream>>>(src, ew, pdeg);
    reduce_kernel<<<(NN + B - 1) / B, B, 0, stream>>>(pdeg, dis, diag);
    bucketA_kernel<<<PA, 256, 0, stream>>>(src, dst, ew, dis, buckets, counts);
    scanS_kernel<<<1, 256, 0, stream>>>(counts, sbase);
    bucketB_kernel<<<SB, 256, 0, stream>>>(buckets, counts, sbase, row_start, csr);

    int pgrid = NN / 4;

    // ---- layer 1: project, then 3 props x 2 packed half-passes ----
    gemm1_kernel<<<dim3((NN + 63) / 64, 4), 256, 0, stream>>>(x, W1, Yf, y3lo, y3hi);
    // u = 4*L(y3) + 2*y2
    prop_half_kernel<unsigned short><<<pgrid, 256, 0, stream>>>(
        y3lo, 4.f, Yf + 128 + 0, 2.f, nullptr, 0.f, nullptr, 0, 32,
        diag, row_start, csr, ulo);
    prop_half_kernel<unsigned short><<<pgrid, 256, 0, stream>>>(
        y3hi, 4.f, Yf + 128 + 32, 2.f, nullptr, 0.f, nullptr, 0, 32,
        diag, row_start, csr, uhi);
    // v = L(u) + y1 - 3*y3
    prop_half_kernel<unsigned short><<<pgrid, 256, 0, stream>>>(
        ulo, 1.f, Yf + 64 + 0, 1.f, Yf + 192 + 0, -3.f, nullptr, 0, 32,
        diag, row_start, csr, vlo);
    prop_half_kernel<unsigned short><<<pgrid, 256, 0, stream>>>(
        uhi, 1.f, Yf + 64 + 32, 1.f, Yf + 192 + 32, -3.f, nullptr, 0, 32,
        diag, row_start, csr, vhi);
    // h = relu(L(v) + y0 - y2 + b1)   (fp32 out, stride 64)
    prop_half_kernel<float><<<pgrid, 256, 0, stream>>>(
        vlo, 1.f, Yf + 0 + 0, 1.f, Yf + 128 + 0, -1.f, b1 + 0, 1, 64,
        diag, row_start, csr, h);
    prop_half_kernel<float><<<pgrid, 256, 0, stream>>>(
        vhi, 1.f, Yf + 0 + 32, 1.f, Yf + 128 + 32, -1.f, b1 + 32, 1, 64,
        diag, row_start, csr, h + 32);

    // ---- layer 2: project, then 3 single-pass props (unchanged) ----
    gemm2_kernel<<<dim3((NN + 127) / 128, 4), 256, 0, stream>>>(h, W2, Y2f, y3b2);
    prop2_kernel<48, unsigned short><<<pgrid, 256, 0, stream>>>(
        y3b2, 64, 4.f, Y2f + 128, 2.f, nullptr, 0.f, 256,
        nullptr, 0, 48, 64, diag, row_start, csr, u2);
    prop2_kernel<48, unsigned short><<<pgrid, 256, 0, stream>>>(
        u2, 64, 1.f, Y2f + 64, 1.f, Y2f + 192, -3.f, 256,
        nullptr, 0, 48, 64, diag, row_start, csr, v2);
    prop2_kernel<48, float><<<pgrid, 256, 0, stream>>>(
        v2, 64, 1.f, Y2f, 1.f, Y2f + 128, -1.f, 256,
        b2, 0, 40, 40, diag, row_start, csr, out);
}

// Round 13
// 525.516 us; speedup vs baseline: 1.2852x; 1.2852x over previous
//
#include <hip/hip_runtime.h>

// Problem constants
#define NN 50000
#define EE 1600000
#define FF 128
#define HH 64
#define CC 40

// deg hist: 64 edge-chunks x 4 node-slices = 256 blocks
#define NCH 64
#define CHE (EE / NCH)         // 25000
#define NSL 4
#define SLN (NN / NSL)         // 12500

// bucket sort: 250 producers x 250 dst-slices (200 nodes each), capacity 64
#define PA 250
#define EPP (EE / PA)          // 6400
#define SB 250
#define SLNB 200               // NN / SB
#define BCAP 64

// ---------- bf16 helpers (storage-only; math in fp32) ----------
static __device__ __forceinline__ float bf2f(unsigned short u) {
    union { unsigned int i; float f; } c; c.i = ((unsigned int)u) << 16; return c.f;
}
static __device__ __forceinline__ unsigned short f2bf(float x) {  // RNE
    union { float f; unsigned int i; } c; c.f = x;
    unsigned int r = c.i + 0x7FFFu + ((c.i >> 16) & 1u);
    return (unsigned short)(r >> 16);
}

// ---------- deg histogram ----------
__global__ __launch_bounds__(1024) void deg_hist_kernel(
    const int* __restrict__ src, const float* __restrict__ w,
    float* __restrict__ pdeg) {
    __shared__ float ldeg[SLN];
    int s = blockIdx.x % NSL;
    int c = blockIdx.x / NSL;
    int base = s * SLN;
    for (int i = threadIdx.x; i < SLN; i += 1024) ldeg[i] = 0.f;
    __syncthreads();
    int e0 = c * CHE;
    for (int e = e0 + threadIdx.x; e < e0 + CHE; e += 1024) {
        int se = src[e];
        unsigned us = (unsigned)(se - base);
        if (us < SLN) atomicAdd(&ldeg[us], w[e]);
    }
    __syncthreads();
    for (int i = threadIdx.x; i < SLN; i += 1024)
        pdeg[(size_t)c * NN + base + i] = ldeg[i];
}

__global__ void reduce_kernel(const float* __restrict__ pdeg,
                              float* __restrict__ dis, float* __restrict__ diag) {
    int n = blockIdx.x * blockDim.x + threadIdx.x;
    if (n >= NN) return;
    float dsum = 0.f;
    for (int c = 0; c < NCH; ++c) dsum += pdeg[(size_t)c * NN + n];
    dis[n]  = (dsum > 0.f) ? rsqrtf(fmaxf(dsum, 1e-12f)) : 0.f;
    diag[n] = (dsum > 0.f) ? 0.f : -1.f;
}

// ---------- phase A: bin edges by dst-slice ----------
__global__ __launch_bounds__(256) void bucketA_kernel(
    const int* __restrict__ src, const int* __restrict__ dst,
    const float* __restrict__ w, const float* __restrict__ dis,
    uint2* __restrict__ buckets, int* __restrict__ counts) {
    __shared__ int lcnt[SB];
    int p = blockIdx.x;
    for (int i = threadIdx.x; i < SB; i += 256) lcnt[i] = 0;
    __syncthreads();
    int e0 = p * EPP;
    for (int e = e0 + threadIdx.x; e < e0 + EPP; e += 256) {
        int de = dst[e], se = src[e];
        int sl = de / SLNB;
        int dl = de - sl * SLNB;
        float wn = -dis[se] * w[e] * dis[de];
        unsigned lo = (unsigned)se | ((unsigned)f2bf(wn) << 16);
        int idx = atomicAdd(&lcnt[sl], 1);
        buckets[((size_t)p * SB + sl) * BCAP + idx] = make_uint2(lo, (unsigned)dl);
    }
    __syncthreads();
    for (int i = threadIdx.x; i < SB; i += 256) counts[p * SB + i] = lcnt[i];
}

// ---------- exclusive scan of per-slice totals ----------
__global__ void scanS_kernel(const int* __restrict__ counts, int* __restrict__ sbase) {
    __shared__ int sh[256];
    int t = threadIdx.x;
    int total = 0;
    if (t < SB)
        for (int p = 0; p < PA; ++p) total += counts[p * SB + t];
    sh[t] = total;
    __syncthreads();
    for (int off = 1; off < 256; off <<= 1) {
        int x = (t >= off) ? sh[t - off] : 0;
        __syncthreads();
        sh[t] += x;
        __syncthreads();
    }
    if (t < SB) sbase[t] = sh[t] - total;
    if (t == SB - 1) sbase[SB] = sh[t];
}

// ---------- phase B v2: counts in LDS + 16-lane bucket subgroups ----------
__global__ __launch_bounds__(256) void bucketB_kernel(
    const uint2* __restrict__ buckets, const int* __restrict__ counts,
    const int* __restrict__ sbase,
    int* __restrict__ row_start, unsigned int* __restrict__ csr) {
    __shared__ int lcounts[PA];
    __shared__ int lhist[SLNB];
    __shared__ int sh[256];
    int s = blockIdx.x;
    int t = threadIdx.x;
    if (t < PA) lcounts[t] = counts[t * SB + s];
    for (int i = t; i < SLNB; i += 256) lhist[i] = 0;
    __syncthreads();
    int g = t >> 4, l16 = t & 15;   // 16 subgroups x 16 lanes
    for (int p = g; p < PA; p += 16) {
        int c = lcounts[p];
        const uint2* b = buckets + ((size_t)p * SB + s) * BCAP;
        for (int i = l16; i < c; i += 16)
            atomicAdd(&lhist[b[i].y], 1);
    }
    __syncthreads();
    int v = (t < SLNB) ? lhist[t] : 0;
    sh[t] = v;
    __syncthreads();
    for (int off = 1; off < 256; off <<= 1) {
        int x = (t >= off) ? sh[t - off] : 0;
        __syncthreads();
        sh[t] += x;
        __syncthreads();
    }
    int base = sbase[s];
    if (t < SLNB) {
        int excl = sh[t] - v;
        row_start[s * SLNB + t] = base + excl;
        lhist[t] = base + excl;          // absolute cursor
    }
    if (s == SB - 1 && t == 0) row_start[NN] = sbase[SB];
    __syncthreads();
    for (int p = g; p < PA; p += 16) {
        int c = lcounts[p];
        const uint2* b = buckets + ((size_t)p * SB + s) * BCAP;
        for (int i = l16; i < c; i += 16) {
            uint2 en = b[i];
            int pos = atomicAdd(&lhist[en.y], 1);
            csr[pos] = en.x;
        }
    }
}

// ---------- propagation: all operands bf16 slabs [N,64] ----------
template <int FACT, typename OUT_T>
__global__ __launch_bounds__(256) void prop2_kernel(
    const unsigned short* __restrict__ a, float alphaL,
    const unsigned short* __restrict__ p1, float beta1,
    const unsigned short* __restrict__ p2, float beta2,
    const float* __restrict__ bias, int doRelu, int FOUT, int outStride,
    const float* __restrict__ diag, const int* __restrict__ rs,
    const unsigned int* __restrict__ csr, OUT_T* __restrict__ out) {
    int lane = threadIdx.x & 63;
    int wave = threadIdx.x >> 6;
    int n = blockIdx.x * 4 + wave;   // NN divisible by 4
    int f = lane;
    float acc = 0.f;
    if (f < FACT) {
        acc = diag[n] * bf2f(a[(size_t)n * 64 + f]);
        int j0 = rs[n], j1 = rs[n + 1];
        int j = j0;
        for (; j + 8 <= j1; j += 8) {
            unsigned cw[8];
            #pragma unroll
            for (int u = 0; u < 8; ++u) cw[u] = csr[j + u];
            float v[8];
            #pragma unroll
            for (int u = 0; u < 8; ++u)
                v[u] = bf2f(a[(size_t)(cw[u] & 0xFFFFu) * 64 + f]);
            #pragma unroll
            for (int u = 0; u < 8; ++u)
                acc = fmaf(bf2f((unsigned short)(cw[u] >> 16)), v[u], acc);
        }
        for (; j < j1; ++j) {
            unsigned cw = csr[j];
            acc = fmaf(bf2f((unsigned short)(cw >> 16)),
                       bf2f(a[(size_t)(cw & 0xFFFFu) * 64 + f]), acc);
        }
    }
    if (f < FOUT) {
        float r = alphaL * acc + beta1 * bf2f(p1[(size_t)n * 64 + f]);
        if (beta2 != 0.f) r = fmaf(beta2, bf2f(p2[(size_t)n * 64 + f]), r);
        if (bias) r += bias[f];
        if (doRelu) r = fmaxf(r, 0.f);
        OUT_T o;
        if constexpr (sizeof(OUT_T) == 2) o = f2bf(r); else o = r;
        out[(size_t)n * outStride + f] = o;
    }
}

// ---------- GEMM1: Yb[ct][n,j] (bf16 [N,64] slabs) = x @ W1[ct] ----------
__global__ __launch_bounds__(256) void gemm1_kernel(
    const float* __restrict__ x, const float* __restrict__ W,
    unsigned short* __restrict__ Yb) {
    __shared__ float As[64][36];
    __shared__ float Bs[32][64];
    int t = threadIdx.x;
    int m0 = blockIdx.x * 64;
    int ct = blockIdx.y;
    int tr = t / 16, tc = t % 16;
    int kq = t % 8,  ms = t / 8;
    int jb = t % 16, fb = t / 16;
    float acc[4][4] = {};
    for (int kb = 0; kb < 4; ++kb) {
        __syncthreads();
        #pragma unroll
        for (int p = 0; p < 2; ++p) {
            int m = ms + 32 * p;
            int row = m0 + m;
            float4 vv = make_float4(0.f, 0.f, 0.f, 0.f);
            if (row < NN) vv = *(const float4*)(x + (size_t)row * FF + kb * 32 + kq * 4);
            *(float4*)&As[m][kq * 4] = vv;
        }
        const float* Wb = W + ((size_t)ct * 128 + kb * 32) * HH;
        #pragma unroll
        for (int p = 0; p < 2; ++p) {
            int fi = fb + 16 * p;
            float4 vv = *(const float4*)(Wb + fi * HH + jb * 4);
            *(float4*)&Bs[fi][jb * 4] = vv;
        }
        __syncthreads();
        #pragma unroll 8
        for (int k = 0; k < 32; ++k) {
            float a0 = As[tr * 4 + 0][k], a1 = As[tr * 4 + 1][k];
            float a2 = As[tr * 4 + 2][k], a3 = As[tr * 4 + 3][k];
            float4 b = *(float4*)&Bs[k][tc * 4];
            acc[0][0] = fmaf(a0, b.x, acc[0][0]); acc[0][1] = fmaf(a0, b.y, acc[0][1]);
            acc[0][2] = fmaf(a0, b.z, acc[0][2]); acc[0][3] = fmaf(a0, b.w, acc[0][3]);
            acc[1][0] = fmaf(a1, b.x, acc[1][0]); acc[1][1] = fmaf(a1, b.y, acc[1][1]);
            acc[1][2] = fmaf(a1, b.z, acc[1][2]); acc[1][3] = fmaf(a1, b.w, acc[1][3]);
            acc[2][0] = fmaf(a2, b.x, acc[2][0]); acc[2][1] = fmaf(a2, b.y, acc[2][1]);
            acc[2][2] = fmaf(a2, b.z, acc[2][2]); acc[2][3] = fmaf(a2, b.w, acc[2][3]);
            acc[3][0] = fmaf(a3, b.x, acc[3][0]); acc[3][1] = fmaf(a3, b.y, acc[3][1]);
            acc[3][2] = fmaf(a3, b.z, acc[3][2]); acc[3][3] = fmaf(a3, b.w, acc[3][3]);
        }
    }
    unsigned short* slab = Yb + (size_t)ct * NN * 64;
    #pragma unroll
    for (int r = 0; r < 4; ++r) {
        int n = m0 + tr * 4 + r;
        if (n < NN) {
            ushort4 u4;
            u4.x = f2bf(acc[r][0]); u4.y = f2bf(acc[r][1]);
            u4.z = f2bf(acc[r][2]); u4.w = f2bf(acc[r][3]);
            *(ushort4*)(slab + (size_t)n * 64 + tc * 4) = u4;
        }
    }
}

// ---------- GEMM2: Zb[kt][n,j] (bf16 [N,64] slabs, cols 40..63 zero) = h @ W2[kt] ----------
__global__ __launch_bounds__(256) void gemm2_kernel(
    const float* __restrict__ h, const float* __restrict__ W,
    unsigned short* __restrict__ Zb) {
    __shared__ float As[128][36];
    __shared__ float Bs[32][40];
    int t = threadIdx.x;
    int m0 = blockIdx.x * 128;
    int kt = blockIdx.y;
    int tr = t / 8, tc = t % 8;
    int kq = t % 8, ms = t / 8;
    float acc[4][5] = {};
    for (int kb = 0; kb < 2; ++kb) {
        __syncthreads();
        #pragma unroll
        for (int p = 0; p < 4; ++p) {
            int m = ms + 32 * p;
            int row = m0 + m;
            float4 vv = make_float4(0.f, 0.f, 0.f, 0.f);
            if (row < NN) vv = *(const float4*)(h + (size_t)row * HH + kb * 32 + kq * 4);
            *(float4*)&As[m][kq * 4] = vv;
        }
        const float* Wb = W + ((size_t)kt * 64 + kb * 32) * CC;
        for (int i = t; i < 32 * CC; i += 256) ((float*)Bs)[i] = Wb[i];
        __syncthreads();
        #pragma unroll 4
        for (int k = 0; k < 32; ++k) {
            float a0 = As[tr * 4 + 0][k], a1 = As[tr * 4 + 1][k];
            float a2 = As[tr * 4 + 2][k], a3 = As[tr * 4 + 3][k];
            #pragma unroll
            for (int c = 0; c < 5; ++c) {
                float b = Bs[k][tc * 5 + c];
                acc[0][c] = fmaf(a0, b, acc[0][c]);
                acc[1][c] = fmaf(a1, b, acc[1][c]);
                acc[2][c] = fmaf(a2, b, acc[2][c]);
                acc[3][c] = fmaf(a3, b, acc[3][c]);
            }
        }
    }
    unsigned short* slab = Zb + (size_t)kt * NN * 64;
    #pragma unroll
    for (int r = 0; r < 4; ++r) {
        int n = m0 + tr * 4 + r;
        if (n < NN) {
            unsigned short* brow = slab + (size_t)n * 64;
            #pragma unroll
            for (int c = 0; c < 5; ++c) brow[tc * 5 + c] = f2bf(acc[r][c]);
            if (tc < 6) {
                #pragma unroll
                for (int c = 0; c < 4; ++c) brow[40 + tc * 4 + c] = 0;
            }
        }
    }
}

// ---------- launcher ----------
extern "C" void kernel_launch(void* const* d_in, const int* in_sizes, int n_in,
                              void* d_out, int out_size, void* d_ws, size_t ws_size,
                              hipStream_t stream) {
    const float* x    = (const float*)d_in[0];
    const int*   eidx = (const int*)d_in[1];
    const float* ew   = (const float*)d_in[2];
    const float* W1   = (const float*)d_in[3];
    const float* b1   = (const float*)d_in[4];
    const float* W2   = (const float*)d_in[5];
    const float* b2   = (const float*)d_in[6];
    float* out = (float*)d_out;

    const int* src = eidx;
    const int* dst = eidx + EE;

    // workspace carve-up  (total ~91 MB)
    float* p = (float*)d_ws;
    unsigned int* csr = (unsigned int*)p;  p += (size_t)EE;           // 6.4 MB
    float* dis  = p;                  p += ((NN + 63) / 64) * 64;
    float* diag = p;                  p += ((NN + 63) / 64) * 64;
    unsigned short* Yb = (unsigned short*)p;  p += (size_t)NN * 128;  // 4 bf16 slabs, 25.6 MB
    unsigned short* u  = (unsigned short*)p;  p += (size_t)NN * 32;   // bf16 [N,64], 6.4 MB
    unsigned short* v  = (unsigned short*)p;  p += (size_t)NN * 32;   // 6.4 MB
    float* h    = p;                  p += (size_t)NN * 64;           // fp32 [N,64], 12.8 MB
    float* scratch = p;               p += (size_t)PA * SB * BCAP * 2; // 32 MB (buckets)
    int* row_start = (int*)p;             // NN+1
    int* counts    = row_start + NN + 1;  // PA*SB
    int* sbase     = counts + PA * SB;    // SB+1

    // setup scratch: pdeg (12.8 MB) and buckets (32 MB) SHARE the 32 MB region.
    // Legal: pdeg is dead after reduce_kernel; bucketA runs strictly after (stream order).
    float* pdeg    = scratch;             // 64*NN floats = 12.8 MB
    uint2* buckets = (uint2*)scratch;     // PA*SB*BCAP*8 B = 32 MB
    // layer-1 slab views
    unsigned short* y0b = Yb;
    unsigned short* y1b = Yb + (size_t)1 * NN * 64;
    unsigned short* y2b = Yb + (size_t)2 * NN * 64;
    unsigned short* y3b = Yb + (size_t)3 * NN * 64;
    // layer-2 slabs alias Yb (y-slabs dead after h)
    unsigned short* Zb = Yb;
    unsigned short* z0 = Zb;
    unsigned short* z1 = Zb + (size_t)1 * NN * 64;
    unsigned short* z2 = Zb + (size_t)2 * NN * 64;
    unsigned short* z3 = Zb + (size_t)3 * NN * 64;
    unsigned short* u2 = u;
    unsigned short* v2 = v;

    const int B = 256;
    deg_hist_kernel<<<NCH * NSL, 1024, 0, stream>>>(src, ew, pdeg);
    reduce_kernel<<<(NN + B - 1) / B, B, 0, stream>>>(pdeg, dis, diag);
    bucketA_kernel<<<PA, 256, 0, stream>>>(src, dst, ew, dis, buckets, counts);
    scanS_kernel<<<1, 256, 0, stream>>>(counts, sbase);
    bucketB_kernel<<<SB, 256, 0, stream>>>(buckets, counts, sbase, row_start, csr);

    int pgrid = NN / 4;

    // ---- layer 1: project to bf16 slabs, then 3 full-width props ----
    gemm1_kernel<<<dim3((NN + 63) / 64, 4), 256, 0, stream>>>(x, W1, Yb);
    prop2_kernel<64, unsigned short><<<pgrid, 256, 0, stream>>>(
        y3b, 4.f, y2b, 2.f, nullptr, 0.f,
        nullptr, 0, 64, 64, diag, row_start, csr, u);          // u = 4*L(y3) + 2*y2
    prop2_kernel<64, unsigned short><<<pgrid, 256, 0, stream>>>(
        u, 1.f, y1b, 1.f, y3b, -3.f,
        nullptr, 0, 64, 64, diag, row_start, csr, v);          // v = L(u) + y1 - 3*y3
    prop2_kernel<64, float><<<pgrid, 256, 0, stream>>>(
        v, 1.f, y0b, 1.f, y2b, -1.f,
        b1, 1, 64, 64, diag, row_start, csr, h);               // h = relu(L(v)+y0-y2+b1)

    // ---- layer 2: project to bf16 slabs, then 3 props ----
    gemm2_kernel<<<dim3((NN + 127) / 128, 4), 256, 0, stream>>>(h, W2, Zb);
    prop2_kernel<48, unsigned short><<<pgrid, 256, 0, stream>>>(
        z3, 4.f, z2, 2.f, nullptr, 0.f,
        nullptr, 0, 48, 64, diag, row_start, csr, u2);         // u2 = 4*L(z3) + 2*z2
    prop2_kernel<48, unsigned short><<<pgrid, 256, 0, stream>>>(
        u2, 1.f, z1, 1.f, z3, -3.f,
        nullptr, 0, 48, 64, diag, row_start, csr, v2);         // v2 = L(u2) + z1 - 3*z3
    prop2_kernel<48, float><<<pgrid, 256, 0, stream>>>(
        v2, 1.f, z0, 1.f, z2, -1.f,
        b2, 0, 40, 40, diag, row_start, csr, out);             // out = L(v2)+z0-z2+b2
}